// Round 10
// baseline (35.148 us; speedup 1.0000x reference)
//
#include <hip/hip_runtime.h>

#define B 64
#define N 1024
#define G 256
#define H 512

// exp(-50*d^2) = 2^(-72.134752*d^2); pre-scale plane coeffs by sqrt(72.134752)
#define S_SCALE 8.4932183f
#define INV_S   (1.0f / S_SCALE)

__device__ __forceinline__ float exp2_fast(float x) {
#if __has_builtin(__builtin_amdgcn_exp2f)
    return __builtin_amdgcn_exp2f(x);   // raw v_exp_f32
#else
    return __expf(x * 0.69314718056f);  // e^(x ln2) = 2^x
#endif
}

// Agent-scope (device) coherent accessors: sc1 write-through / L2-bypass.
// These make cross-XCD communication correct WITHOUT __threadfence's
// buffer_wbl2 (r4/r5 lesson: per-wave L2 writeback fences cost ~135us).
__device__ __forceinline__ void st_agent(float* p, float v) {
    __hip_atomic_store(p, v, __ATOMIC_RELAXED, __HIP_MEMORY_SCOPE_AGENT);
}
__device__ __forceinline__ float ld_agent(const float* p) {
    return __hip_atomic_load(p, __ATOMIC_RELAXED, __HIP_MEMORY_SCOPE_AGENT);
}

// ---------------------------------------------------------------------------
// Node A: stable top-k (k=G=256) via O(N^2) ranking, j-split 4 ways.
// 4 blocks per batch x 1024 threads (16 waves = 4 waves/SIMD hides latency).
// rank semantics == lax.top_k: descending, ties -> lower original index.
// Also zeroes the per-batch finalize counter for node B (visible via the
// end-of-kernel release).
// ---------------------------------------------------------------------------
#define TKB 4  // blocks per batch

__global__ __launch_bounds__(1024) void topk_gather_kernel(
    const float* __restrict__ pts,        // (B,3,N)
    const float* __restrict__ pt_weight,  // (B,N)
    float* __restrict__ out_gpts,         // (B,G,3)
    int* __restrict__ cnt)                // (B)
{
    const int b = blockIdx.x / TKB;
    const int q = blockIdx.x % TKB;
    const int tid = threadIdx.x;

    __shared__ float w[N];
    __shared__ int part[4][256];

    w[tid] = pt_weight[(size_t)b * N + tid];
    if (q == 0 && tid == 0) cnt[b] = 0;
    __syncthreads();

    const int e = tid & 255;
    const int p = tid >> 8;            // j-quarter (wave-uniform: 4 waves per p)
    const int i = (q << 8) + e;        // global element index
    const float wi = w[i];
    const float* wq = w + (p << 8);

    int r = 0;
    if (p < q) {            // all j < i: ties count
        #pragma unroll 8
        for (int j = 0; j < 256; j += 4) {
            const float4 wj = *(const float4*)(wq + j);
            r += (wj.x >= wi) + (wj.y >= wi) + (wj.z >= wi) + (wj.w >= wi);
        }
    } else if (p > q) {     // all j > i: ties don't count
        #pragma unroll 8
        for (int j = 0; j < 256; j += 4) {
            const float4 wj = *(const float4*)(wq + j);
            r += (wj.x > wi) + (wj.y > wi) + (wj.z > wi) + (wj.w > wi);
        }
    } else {                // mixed quarter: j and i in same 256-range
        const int j0 = p << 8;
        #pragma unroll 8
        for (int j = 0; j < 256; j += 4) {
            const float4 wj = *(const float4*)(wq + j);
            r += (wj.x > wi) || (wj.x == wi && (j0 + j + 0) < i);
            r += (wj.y > wi) || (wj.y == wi && (j0 + j + 1) < i);
            r += (wj.z > wi) || (wj.z == wi && (j0 + j + 2) < i);
            r += (wj.w > wi) || (wj.w == wi && (j0 + j + 3) < i);
        }
    }
    part[p][e] = r;
    __syncthreads();

    if (p == 0) {
        const int rank = part[0][e] + part[1][e] + part[2][e] + part[3][e];
        if (rank < G) {
            float* dst = out_gpts + ((size_t)b * G + rank) * 3;
            dst[0] = pts[b * 3 * N + 0 * N + i];
            dst[1] = pts[b * 3 * N + 1 * N + i];
            dst[2] = pts[b * 3 * N + 2 * N + i];
        }
    }
}

// ---------------------------------------------------------------------------
// Node B: plane + score + loss (1024 blocks, proven ~4us shape), THEN the
// last-arriving block of each batch finalizes. Cross-block publication uses
// agent-scope atomic stores + per-wave vmcnt(0) drain + relaxed agent
// atomicAdd counter; finalizer reads via agent-scope atomic loads.
// NO fences (no buffer_wbl2), dispatch-order independent, no spinning.
// ---------------------------------------------------------------------------
__global__ __launch_bounds__(256) void plane_finalize_kernel(
    const float* __restrict__ pts,      // (B,3,N)
    const float* __restrict__ target,   // (B,3)
    const int* __restrict__ sel_idx,    // (B,H,3)
    const float* __restrict__ gpts,     // (B,G,3) [in d_out, from node A]
    float* __restrict__ out,            // exp_loss(B)|top_loss(B)|pred(3B)|gpts
    float* __restrict__ score,          // ws (B,H)
    float* __restrict__ loss,           // ws (B,H)
    float* __restrict__ normals,        // ws (B,H,3)
    int* __restrict__ cnt)              // ws (B)
{
    __shared__ float sp[3 * N];   // 12 KB
    __shared__ float gp[3 * G];   // 3 KB
    __shared__ float sv[4]; __shared__ int sidx[4];
    __shared__ float ssw[4], sswl[4];
    __shared__ float s_max; __shared__ int s_maxi;
    __shared__ bool s_last;

    const int blk = blockIdx.x;
    const int tid = threadIdx.x;
    const int b   = blk >> 4;   // 64 batches
    const int hg  = blk & 15;   // 16 hypothesis-groups per batch
    const int wave = tid >> 6;
    const int lane = tid & 63;

    {
        const float4* ps = (const float4*)(pts + (size_t)b * 3 * N);
        float4* spv = (float4*)sp;
        spv[tid]       = ps[tid];
        spv[tid + 256] = ps[tid + 256];
        spv[tid + 512] = ps[tid + 512];
        if (tid < 192)
            ((float4*)gp)[tid] = ((const float4*)(gpts + (size_t)b * 3 * G))[tid];
    }
    __syncthreads();

    const int h0 = (hg << 5) + (wave << 3);  // 32 hyps/block, 8/wave
    float nx[8], ny[8], nz[8], pd[8], acc[8];

    #pragma unroll   // FULL unroll: hh must be compile-time (rule #20)
    for (int hh = 0; hh < 8; ++hh) {
        const int* si = sel_idx + ((size_t)b * H + h0 + hh) * 3;
        const int g0 = si[0] * 3, g1 = si[1] * 3, g2 = si[2] * 3;
        const float p0x = gp[g0], p0y = gp[g0 + 1], p0z = gp[g0 + 2];
        const float p1x = gp[g1], p1y = gp[g1 + 1], p1z = gp[g1 + 2];
        const float p2x = gp[g2], p2y = gp[g2 + 1], p2z = gp[g2 + 2];
        const float e1x = p1x - p0x, e1y = p1y - p0y, e1z = p1z - p0z;
        const float e2x = p2x - p0x, e2y = p2y - p0y, e2z = p2z - p0z;
        float x = e1y * e2z - e1z * e2y;
        float y = e1z * e2x - e1x * e2z;
        float z = e1x * e2y - e1y * e2x;
        float d = -(x * p0x + y * p0y + z * p0z);
        if (x == 0.f && y == 0.f && z == 0.f && d == 0.f) { x = y = z = d = 1.f; }
        const float ns = S_SCALE / sqrtf(x * x + y * y + z * z);
        nx[hh] = x * ns; ny[hh] = y * ns; nz[hh] = z * ns; pd[hh] = d * ns;
        acc[hh] = 0.f;
    }

    #pragma unroll 4
    for (int k = 0; k < N / 64; ++k) {
        const int n = lane + (k << 6);
        const float px = sp[n], py = sp[N + n], pz = sp[2 * N + n];
        #pragma unroll
        for (int hh = 0; hh < 8; ++hh) {
            const float u = fmaf(nx[hh], px, fmaf(ny[hh], py, fmaf(nz[hh], pz, pd[hh])));
            acc[hh] += exp2_fast(-(u * u));  // neg folds into v_exp src modifier
        }
    }

    const float tx = target[b * 3 + 0], ty = target[b * 3 + 1], tz = target[b * 3 + 2];
    #pragma unroll
    for (int hh = 0; hh < 8; ++hh) {
        float a = acc[hh];
        #pragma unroll
        for (int off = 32; off; off >>= 1) a += __shfl_xor(a, off);
        if (lane == 0) {
            const float x = nx[hh] * INV_S, y = ny[hh] * INV_S, z = nz[hh] * INV_S;
            const float l1 = (x - tx) * (x - tx) + (y - ty) * (y - ty) + (z - tz) * (z - tz);
            const float l2 = (x + tx) * (x + tx) + (y + ty) * (y + ty) + (z + tz) * (z + tz);
            const int idx = b * H + h0 + hh;
            st_agent(&score[idx], a);                  // sc1: coherent publish
            st_agent(&loss[idx], fminf(l1, l2));
            st_agent(&normals[idx * 3 + 0], x);
            st_agent(&normals[idx * 3 + 1], y);
            st_agent(&normals[idx * 3 + 2], z);
        }
    }

    // Per-wave store-completion drain (release without wbl2), then count in.
    asm volatile("s_waitcnt vmcnt(0)" ::: "memory");
    __syncthreads();
    if (tid == 0) {
        const int prev = __hip_atomic_fetch_add(&cnt[b], 1, __ATOMIC_RELAXED,
                                                __HIP_MEMORY_SCOPE_AGENT);
        s_last = (prev == 15);
    }
    __syncthreads();
    if (!s_last) return;

    // ---------------- finalize (last block of batch b) ----------------
    {
        const float* sc = score + b * H;
        const float* ls = loss + b * H;
        const float s0 = ld_agent(&sc[tid]),       s1 = ld_agent(&sc[tid + 256]);
        const float l0 = ld_agent(&ls[tid]),       l1 = ld_agent(&ls[tid + 256]);

        float v; int vi;
        if (s1 > s0) { v = s1; vi = tid + 256; } else { v = s0; vi = tid; }
        #pragma unroll
        for (int off = 32; off; off >>= 1) {
            const float v2 = __shfl_xor(v, off);
            const int i2 = __shfl_xor(vi, off);
            if (v2 > v || (v2 == v && i2 < vi)) { v = v2; vi = i2; }
        }
        if (lane == 0) { sv[wave] = v; sidx[wave] = vi; }
        __syncthreads();

        if (tid == 0) {
            float bv = sv[0]; int bi = sidx[0];
            #pragma unroll
            for (int k = 1; k < 4; ++k) {
                if (sv[k] > bv || (sv[k] == bv && sidx[k] < bi)) { bv = sv[k]; bi = sidx[k]; }
            }
            s_max = bv; s_maxi = bi;
        }
        __syncthreads();

        const float m = s_max;
        const float w0 = __expf(0.5f * (s0 - m)), w1 = __expf(0.5f * (s1 - m));
        float tw = w0 + w1;
        float twl = w0 * l0 + w1 * l1;
        #pragma unroll
        for (int off = 32; off; off >>= 1) {
            tw += __shfl_xor(tw, off);
            twl += __shfl_xor(twl, off);
        }
        if (lane == 0) { ssw[wave] = tw; sswl[wave] = twl; }
        __syncthreads();

        if (tid == 0) {
            const float TW = ssw[0] + ssw[1] + ssw[2] + ssw[3];
            const float TWL = sswl[0] + sswl[1] + sswl[2] + sswl[3];
            const int mi = s_maxi;
            out[b] = TWL / TW;                          // exp_loss
            out[B + b] = ld_agent(&ls[mi]);             // top_loss
            out[2 * B + b * 3 + 0] = ld_agent(&normals[((size_t)b * H + mi) * 3 + 0]);
            out[2 * B + b * 3 + 1] = ld_agent(&normals[((size_t)b * H + mi) * 3 + 1]);
            out[2 * B + b * 3 + 2] = ld_agent(&normals[((size_t)b * H + mi) * 3 + 2]);
        }
    }
}

// ---------------------------------------------------------------------------
extern "C" void kernel_launch(void* const* d_in, const int* in_sizes, int n_in,
                              void* d_out, int out_size, void* d_ws, size_t ws_size,
                              hipStream_t stream) {
    const float* pts       = (const float*)d_in[0];  // (B,3,N)
    const float* target    = (const float*)d_in[1];  // (B,3)
    const float* pt_weight = (const float*)d_in[2];  // (B,N)
    const int*   sel_idx   = (const int*)d_in[3];    // (B,H,3)

    float* out = (float*)d_out;
    // layout: exp_loss[B] | top_loss[B] | pred[B*3] | gpts[B*G*3]
    float* out_gpts = out + 5 * B;

    float* ws      = (float*)d_ws;
    float* score   = ws;                      // B*H
    float* loss    = ws + B * H;              // B*H
    float* normals = ws + 2 * B * H;          // B*H*3
    int*   cnt     = (int*)(ws + 5 * B * H);  // B

    topk_gather_kernel<<<B * TKB, 1024, 0, stream>>>(pts, pt_weight, out_gpts, cnt);
    plane_finalize_kernel<<<B * 16, 256, 0, stream>>>(pts, target, sel_idx, out_gpts,
                                                      out, score, loss, normals, cnt);
}

// Round 11
// 34.169 us; speedup vs baseline: 1.0287x; 1.0287x over previous
//
#include <hip/hip_runtime.h>

#define B 64
#define N 1024
#define G 256
#define H 512

// exp(-50*d^2) = 2^(-72.134752*d^2); pre-scale plane coeffs by sqrt(72.134752)
#define S_SCALE 8.4932183f
#define INV_S   (1.0f / S_SCALE)

__device__ __forceinline__ float exp2_fast(float x) {
#if __has_builtin(__builtin_amdgcn_exp2f)
    return __builtin_amdgcn_exp2f(x);   // raw v_exp_f32
#else
    return __expf(x * 0.69314718056f);  // e^(x ln2) = 2^x
#endif
}

// ---------------------------------------------------------------------------
// Kernel 1: stable top-k (k=G=256) via O(N^2) ranking, j-split 4 ways.
// 4 blocks per batch x 1024 threads (16 waves = 4 waves/SIMD hides latency).
// rank semantics == lax.top_k: descending, ties -> lower original index.
// ---------------------------------------------------------------------------
#define TKB 4  // blocks per batch

__global__ __launch_bounds__(1024) void topk_gather_kernel(
    const float* __restrict__ pts,        // (B,3,N)
    const float* __restrict__ pt_weight,  // (B,N)
    float* __restrict__ out_gpts)         // (B,G,3)
{
    const int b = blockIdx.x / TKB;
    const int q = blockIdx.x % TKB;
    const int tid = threadIdx.x;

    __shared__ float w[N];
    __shared__ int part[4][256];

    w[tid] = pt_weight[(size_t)b * N + tid];
    __syncthreads();

    const int e = tid & 255;
    const int p = tid >> 8;            // j-quarter (wave-uniform: 4 waves per p)
    const int i = (q << 8) + e;        // global element index
    const float wi = w[i];
    const float* wq = w + (p << 8);

    int r = 0;
    if (p < q) {            // all j < i: ties count
        #pragma unroll 8
        for (int j = 0; j < 256; j += 4) {
            const float4 wj = *(const float4*)(wq + j);
            r += (wj.x >= wi) + (wj.y >= wi) + (wj.z >= wi) + (wj.w >= wi);
        }
    } else if (p > q) {     // all j > i: ties don't count
        #pragma unroll 8
        for (int j = 0; j < 256; j += 4) {
            const float4 wj = *(const float4*)(wq + j);
            r += (wj.x > wi) + (wj.y > wi) + (wj.z > wi) + (wj.w > wi);
        }
    } else {                // mixed quarter: j and i in same 256-range
        const int j0 = p << 8;
        #pragma unroll 8
        for (int j = 0; j < 256; j += 4) {
            const float4 wj = *(const float4*)(wq + j);
            r += (wj.x > wi) || (wj.x == wi && (j0 + j + 0) < i);
            r += (wj.y > wi) || (wj.y == wi && (j0 + j + 1) < i);
            r += (wj.z > wi) || (wj.z == wi && (j0 + j + 2) < i);
            r += (wj.w > wi) || (wj.w == wi && (j0 + j + 3) < i);
        }
    }
    part[p][e] = r;
    __syncthreads();

    if (p == 0) {
        const int rank = part[0][e] + part[1][e] + part[2][e] + part[3][e];
        if (rank < G) {
            float* dst = out_gpts + ((size_t)b * G + rank) * 3;
            dst[0] = pts[b * 3 * N + 0 * N + i];
            dst[1] = pts[b * 3 * N + 1 * N + i];
            dst[2] = pts[b * 3 * N + 2 * N + i];
        }
    }
}

// ---------------------------------------------------------------------------
// Kernel 2: plane + score + loss. REGISTER-RESIDENT POINTS: each lane holds
// 16 points (12 x float4 = 48 VGPR) loaded via coalesced 16B global loads
// (L2-served; all 64 waves of a batch share the same 12KB). Inner loop is
// pure register FMA + exp with 8-way ILP — no LDS reads to stall on
// (r8 evidence: LDS-fed version was latency-bound, VALUBusy 18.6%).
// Only gp (gathered points, 3KB) stays in LDS for the hypothesis setup.
// ---------------------------------------------------------------------------
__global__ __launch_bounds__(256) void plane_score_kernel(
    const float* __restrict__ pts,      // (B,3,N)
    const float* __restrict__ target,   // (B,3)
    const int* __restrict__ sel_idx,    // (B,H,3)
    const float* __restrict__ gpts,     // (B,G,3) [in d_out, from kernel 1]
    float* __restrict__ score,          // ws (B,H)
    float* __restrict__ loss,           // ws (B,H)
    float* __restrict__ normals)        // ws (B,H,3)
{
    __shared__ float gp[3 * G];   // 3 KB
    const int blk = blockIdx.x;
    const int tid = threadIdx.x;
    const int b   = blk >> 4;   // 64 batches
    const int hg  = blk & 15;   // 16 hypothesis-groups per batch
    const int wave = tid >> 6;
    const int lane = tid & 63;

    if (tid < 192)
        ((float4*)gp)[tid] = ((const float4*)(gpts + (size_t)b * 3 * G))[tid];

    // Load this lane's 16 points into registers while gp staging lands.
    // Lane l takes n = k*256 + 4l + {0,1,2,3}: 16B/lane coalesced loads.
    const float* pb = pts + (size_t)b * 3 * N;
    float4 px[4], py[4], pz[4];
    #pragma unroll
    for (int k = 0; k < 4; ++k) {
        const int n4 = (k << 8) + (lane << 2);
        px[k] = *(const float4*)(pb + n4);
        py[k] = *(const float4*)(pb + N + n4);
        pz[k] = *(const float4*)(pb + 2 * N + n4);
    }
    __syncthreads();

    const int h0 = (hg << 5) + (wave << 3);  // 32 hyps/block, 8/wave
    float nx[8], ny[8], nz[8], pd[8], acc[8];

    #pragma unroll   // FULL unroll: hh must be compile-time (rule #20)
    for (int hh = 0; hh < 8; ++hh) {
        const int* si = sel_idx + ((size_t)b * H + h0 + hh) * 3;
        const int g0 = si[0] * 3, g1 = si[1] * 3, g2 = si[2] * 3;
        const float p0x = gp[g0], p0y = gp[g0 + 1], p0z = gp[g0 + 2];
        const float p1x = gp[g1], p1y = gp[g1 + 1], p1z = gp[g1 + 2];
        const float p2x = gp[g2], p2y = gp[g2 + 1], p2z = gp[g2 + 2];
        const float e1x = p1x - p0x, e1y = p1y - p0y, e1z = p1z - p0z;
        const float e2x = p2x - p0x, e2y = p2y - p0y, e2z = p2z - p0z;
        float x = e1y * e2z - e1z * e2y;
        float y = e1z * e2x - e1x * e2z;
        float z = e1x * e2y - e1y * e2x;
        float d = -(x * p0x + y * p0y + z * p0z);
        if (x == 0.f && y == 0.f && z == 0.f && d == 0.f) { x = y = z = d = 1.f; }
        const float ns = S_SCALE / sqrtf(x * x + y * y + z * z);
        nx[hh] = x * ns; ny[hh] = y * ns; nz[hh] = z * ns; pd[hh] = d * ns;
        acc[hh] = 0.f;
    }

    #pragma unroll
    for (int k = 0; k < 4; ++k) {
        #pragma unroll
        for (int hh = 0; hh < 8; ++hh) {
            const float u0 = fmaf(nx[hh], px[k].x, fmaf(ny[hh], py[k].x, fmaf(nz[hh], pz[k].x, pd[hh])));
            const float u1 = fmaf(nx[hh], px[k].y, fmaf(ny[hh], py[k].y, fmaf(nz[hh], pz[k].y, pd[hh])));
            const float u2 = fmaf(nx[hh], px[k].z, fmaf(ny[hh], py[k].z, fmaf(nz[hh], pz[k].z, pd[hh])));
            const float u3 = fmaf(nx[hh], px[k].w, fmaf(ny[hh], py[k].w, fmaf(nz[hh], pz[k].w, pd[hh])));
            acc[hh] += exp2_fast(-(u0 * u0));
            acc[hh] += exp2_fast(-(u1 * u1));
            acc[hh] += exp2_fast(-(u2 * u2));
            acc[hh] += exp2_fast(-(u3 * u3));
        }
    }

    const float tx = target[b * 3 + 0], ty = target[b * 3 + 1], tz = target[b * 3 + 2];
    #pragma unroll
    for (int hh = 0; hh < 8; ++hh) {
        float a = acc[hh];
        #pragma unroll
        for (int off = 32; off; off >>= 1) a += __shfl_xor(a, off);
        if (lane == 0) {
            const float x = nx[hh] * INV_S, y = ny[hh] * INV_S, z = nz[hh] * INV_S;
            const float l1 = (x - tx) * (x - tx) + (y - ty) * (y - ty) + (z - tz) * (z - tz);
            const float l2 = (x + tx) * (x + tx) + (y + ty) * (y + ty) + (z + tz) * (z + tz);
            const int idx = b * H + h0 + hh;
            score[idx] = a;
            loss[idx] = fminf(l1, l2);
            normals[idx * 3 + 0] = x;
            normals[idx * 3 + 1] = y;
            normals[idx * 3 + 2] = z;
        }
    }
}

// ---------------------------------------------------------------------------
// Kernel 3: per batch finalize: argmax (tie -> first), stable softmax of
// 0.5*score, exp_loss, top_loss, pred. 256 threads, 2 hyps each.
// ---------------------------------------------------------------------------
__global__ __launch_bounds__(256) void finalize_kernel(
    const float* __restrict__ score,    // (B,H)
    const float* __restrict__ loss,     // (B,H)
    const float* __restrict__ normals,  // (B,H,3)
    float* __restrict__ out)            // exp_loss(B)|top_loss(B)|pred(3B)|gpts...
{
    const int b = blockIdx.x;
    const int tid = threadIdx.x;
    const int wave = tid >> 6;
    const int lane = tid & 63;

    __shared__ float sv[4]; __shared__ int sidx[4];
    __shared__ float ssw[4], sswl[4];
    __shared__ float s_max; __shared__ int s_maxi;

    const float* sc = score + b * H;
    const float* ls = loss + b * H;
    const float s0 = sc[tid], s1 = sc[tid + 256];

    float v; int vi;
    if (s1 > s0) { v = s1; vi = tid + 256; } else { v = s0; vi = tid; }
    #pragma unroll
    for (int off = 32; off; off >>= 1) {
        const float v2 = __shfl_xor(v, off);
        const int i2 = __shfl_xor(vi, off);
        if (v2 > v || (v2 == v && i2 < vi)) { v = v2; vi = i2; }
    }
    if (lane == 0) { sv[wave] = v; sidx[wave] = vi; }
    __syncthreads();

    if (tid == 0) {
        float bv = sv[0]; int bi = sidx[0];
        #pragma unroll
        for (int k = 1; k < 4; ++k) {
            if (sv[k] > bv || (sv[k] == bv && sidx[k] < bi)) { bv = sv[k]; bi = sidx[k]; }
        }
        s_max = bv; s_maxi = bi;
    }
    __syncthreads();

    const float m = s_max;
    const float w0 = __expf(0.5f * (s0 - m)), w1 = __expf(0.5f * (s1 - m));
    float tw = w0 + w1;
    float twl = w0 * ls[tid] + w1 * ls[tid + 256];
    #pragma unroll
    for (int off = 32; off; off >>= 1) {
        tw += __shfl_xor(tw, off);
        twl += __shfl_xor(twl, off);
    }
    if (lane == 0) { ssw[wave] = tw; sswl[wave] = twl; }
    __syncthreads();

    if (tid == 0) {
        const float TW = ssw[0] + ssw[1] + ssw[2] + ssw[3];
        const float TWL = sswl[0] + sswl[1] + sswl[2] + sswl[3];
        const int mi = s_maxi;
        out[b] = TWL / TW;                               // exp_loss
        out[B + b] = ls[mi];                             // top_loss
        out[2 * B + b * 3 + 0] = normals[((size_t)b * H + mi) * 3 + 0];
        out[2 * B + b * 3 + 1] = normals[((size_t)b * H + mi) * 3 + 1];
        out[2 * B + b * 3 + 2] = normals[((size_t)b * H + mi) * 3 + 2];
    }
}

// ---------------------------------------------------------------------------
extern "C" void kernel_launch(void* const* d_in, const int* in_sizes, int n_in,
                              void* d_out, int out_size, void* d_ws, size_t ws_size,
                              hipStream_t stream) {
    const float* pts       = (const float*)d_in[0];  // (B,3,N)
    const float* target    = (const float*)d_in[1];  // (B,3)
    const float* pt_weight = (const float*)d_in[2];  // (B,N)
    const int*   sel_idx   = (const int*)d_in[3];    // (B,H,3)

    float* out = (float*)d_out;
    // layout: exp_loss[B] | top_loss[B] | pred[B*3] | gpts[B*G*3]
    float* out_gpts = out + 5 * B;

    float* ws      = (float*)d_ws;
    float* score   = ws;                      // B*H
    float* loss    = ws + B * H;              // B*H
    float* normals = ws + 2 * B * H;          // B*H*3

    topk_gather_kernel<<<B * TKB, 1024, 0, stream>>>(pts, pt_weight, out_gpts);
    plane_score_kernel<<<B * 16, 256, 0, stream>>>(pts, target, sel_idx, out_gpts,
                                                   score, loss, normals);
    finalize_kernel<<<B, 256, 0, stream>>>(score, loss, normals, out);
}